// Round 9
// baseline (283.742 us; speedup 1.0000x reference)
//
#include <hip/hip_runtime.h>
#include <hip/hip_bf16.h>
#include <math.h>

#define SS 160
#define DD 512
#define HH 8
#define MTOK 640
#define FFD 2048
#define NTT 257   // T+1 time-embedding rows

typedef __attribute__((ext_vector_type(8))) short bfrag8;
typedef __attribute__((ext_vector_type(4))) float facc4;
typedef unsigned short u16;

#define SWZ(row, cb) ((cb) ^ (((row)&7) << 4))

__device__ __forceinline__ void gload16(const void* g, void* l) {
  __builtin_amdgcn_global_load_lds(
      (const __attribute__((address_space(1))) void*)g,
      (__attribute__((address_space(3))) void*)l, 16, 0, 0);
}

__device__ __forceinline__ u16 f2b(float f) {
  __hip_bfloat16 hb = __float2bfloat16(f);
  return *reinterpret_cast<u16*>(&hb);
}

// ================= prep_all ================================================
__device__ void wconv_body(const float* __restrict__ src,
                           __hip_bfloat16* __restrict__ dst,
                           int K, int N, int dls, int rowoff,
                           int l, int bx, int by, float (*tile)[65])
{
  src += (size_t)l * K * N;
  dst += (size_t)l * dls + (size_t)rowoff * K;
  int k0 = by * 64, n0 = bx * 64;
  int t = threadIdx.x;
  int r = t >> 2, c0 = (t & 3) * 16;
  #pragma unroll
  for (int j = 0; j < 16; j += 4) {
    float4 v4 = *(const float4*)&src[(size_t)(k0 + r) * N + n0 + c0 + j];
    tile[r][c0 + j + 0] = v4.x; tile[r][c0 + j + 1] = v4.y;
    tile[r][c0 + j + 2] = v4.z; tile[r][c0 + j + 3] = v4.w;
  }
  __syncthreads();
  union { u16 u[8]; uint4 v; } pk;
  #pragma unroll
  for (int half = 0; half < 2; ++half) {
    #pragma unroll
    for (int j = 0; j < 8; ++j)
      pk.u[j] = f2b(tile[c0 + half * 8 + j][r]);
    *(uint4*)&dst[(size_t)(n0 + r) * K + k0 + c0 + half * 8] = pk.v;
  }
}

__global__ __launch_bounds__(256) void prep_all(
    const float* __restrict__ Wq, const float* __restrict__ Wk,
    const float* __restrict__ Wv, const float* __restrict__ Wo,
    const float* __restrict__ W1, const float* __restrict__ W2,
    const float* __restrict__ tiK,
    __hip_bfloat16* __restrict__ wqkv, __hip_bfloat16* __restrict__ wo_t,
    __hip_bfloat16* __restrict__ w1_t, __hip_bfloat16* __restrict__ w2_t,
    __hip_bfloat16* __restrict__ tikb,
    const int* __restrict__ x, const int* __restrict__ stamp,
    const float* __restrict__ tok, const float* __restrict__ month,
    const float* __restrict__ day, const float* __restrict__ g0,
    const float* __restrict__ b0, float* __restrict__ h,
    __hip_bfloat16* __restrict__ hb)
{
  __shared__ float tile[64][65];
  __shared__ float ssh[4], qsh[4];
  int idx = blockIdx.x;
  int tid = threadIdx.x;

  if (idx < 1536) {
    if (idx < 384) {
      int grp = idx / 128, r = idx % 128;
      int l = r / 64, t = r % 64;
      const float* src = grp == 0 ? Wq : (grp == 1 ? Wk : Wv);
      wconv_body(src, wqkv, 512, 512, 1536 * 512, 512 * grp, l, t % 8, t / 8, tile);
    } else if (idx < 512) {
      int r = idx - 384; int l = r / 64, t = r % 64;
      wconv_body(Wo, wo_t, 512, 512, 512 * 512, 0, l, t % 8, t / 8, tile);
    } else if (idx < 1024) {
      int r = idx - 512; int l = r / 256, t = r % 256;
      wconv_body(W1, w1_t, 512, 2048, 2048 * 512, 0, l, t % 32, t / 32, tile);
    } else {
      int r = idx - 1024; int l = r / 256, t = r % 256;
      wconv_body(W2, w2_t, 2048, 512, 512 * 2048, 0, l, t % 8, t / 8, tile);
    }
  } else if (idx < 1665) {
    int i = (idx - 1536) * 256 + tid;
    if (i < NTT * DD / 4) {
      float4 v = *(const float4*)(tiK + (size_t)i * 4);
      union { u16 u[4]; uint2 w; } pk;
      pk.u[0] = f2b(v.x); pk.u[1] = f2b(v.y);
      pk.u[2] = f2b(v.z); pk.u[3] = f2b(v.w);
      *(uint2*)(tikb + (size_t)i * 4) = pk.w;
    }
  } else {
    int m = idx - 1665;
    int b = m / SS, s = m % SS, t = tid;
    int tokid = x[m];
    float v0 = tok[tokid * DD + t];
    float v1 = tok[tokid * DD + t + 256];
    if (s > 0) {
      int sidx = (b * (SS - 1) + (s - 1)) * 3;
      int mo = stamp[sidx + 0], dy = stamp[sidx + 1];
      v0 += month[mo * DD + t]       + day[dy * DD + t];
      v1 += month[mo * DD + t + 256] + day[dy * DD + t + 256];
    }
    float sum = v0 + v1, sq = v0 * v0 + v1 * v1;
    #pragma unroll
    for (int off = 1; off < 64; off <<= 1) {
      sum += __shfl_xor(sum, off);
      sq  += __shfl_xor(sq , off);
    }
    if ((t & 63) == 0) { ssh[t >> 6] = sum; qsh[t >> 6] = sq; }
    __syncthreads();
    float fsum = ssh[0] + ssh[1] + ssh[2] + ssh[3];
    float fsq  = qsh[0] + qsh[1] + qsh[2] + qsh[3];
    float u = fsum * (1.0f / 512.0f);
    float var = fsq * (1.0f / 512.0f) - u * u;
    float r = rsqrtf(var + 1e-12f);
    float y0 = g0[t]       * ((v0 - u) * r) + b0[t];
    float y1 = g0[t + 256] * ((v1 - u) * r) + b0[t + 256];
    h[m * DD + t]        = y0;  h[m * DD + t + 256]  = y1;
    hb[m * DD + t]       = __float2bfloat16(y0);
    hb[m * DD + t + 256] = __float2bfloat16(y1);
  }
}

// ========== pipelined MFMA GEMM (LDS-staged) ==========
#define EPI_GELU 2
#define EPI_QKV 3

template<int EPI, int K>
__global__ __launch_bounds__(256) void gemm_ck(
    const __hip_bfloat16* __restrict__ A,
    const __hip_bfloat16* __restrict__ Bt,
    const float* __restrict__ bias,
    const float* __restrict__ bias2,
    const float* __restrict__ bias3,
    __hip_bfloat16* __restrict__ Cb,
    int N)
{
  constexpr int KC = 128;
  constexpr int NCH = K / KC;
  __shared__ u16 As[2][64 * KC];
  __shared__ u16 Bs[2][64 * KC];
  const int tid = threadIdx.x, wv = tid >> 6, lane = tid & 63;
  const int m0 = blockIdx.y * 64, n0 = blockIdx.x * 64;
  const int wr = wv >> 1, wc = wv & 1;
  const int fr = lane & 15, fks = lane >> 4;

  const int ldsq = (wv * 4) * 1024;
  const int off0 = ldsq + lane * 16;

  #define STAGE(c, buf) do {                                                  \
    _Pragma("unroll")                                                         \
    for (int i_ = 0; i_ < 4; ++i_) {                                          \
      int ldso = ldsq + i_ * 1024;                                            \
      int off = off0 + i_ * 1024;                                             \
      int r_ = off >> 8;                                                      \
      int p_ = off & 255;                                                     \
      int ps_ = p_ ^ ((r_ & 7) << 4);                                         \
      gload16((const char*)A  + ((size_t)(m0 + r_) * K + (c) * KC) * 2 + ps_, \
              (char*)&As[buf][0] + ldso);                                     \
      gload16((const char*)Bt + ((size_t)(n0 + r_) * K + (c) * KC) * 2 + ps_, \
              (char*)&Bs[buf][0] + ldso);                                     \
    }                                                                         \
  } while (0)

  facc4 acc[2][2] = {};
  STAGE(0, 0);
  STAGE(1, 1);

  #pragma unroll
  for (int c = 0; c < NCH; ++c) {
    if (c + 1 < NCH) asm volatile("s_waitcnt vmcnt(8)\n\ts_barrier" ::: "memory");
    else             asm volatile("s_waitcnt vmcnt(0)\n\ts_barrier" ::: "memory");
    const char* ab = (const char*)&As[c & 1][0];
    const char* bb = (const char*)&Bs[c & 1][0];
    #pragma unroll
    for (int ks = 0; ks < 4; ++ks) {
      bfrag8 af[2], bfv[2];
      #pragma unroll
      for (int mf = 0; mf < 2; ++mf) {
        int rA = wr * 32 + mf * 16 + fr;
        af[mf] = *(const bfrag8*)(ab + rA * 256 + SWZ(rA, ks * 64 + fks * 16));
      }
      #pragma unroll
      for (int nf = 0; nf < 2; ++nf) {
        int rB = wc * 32 + nf * 16 + fr;
        bfv[nf] = *(const bfrag8*)(bb + rB * 256 + SWZ(rB, ks * 64 + fks * 16));
      }
      #pragma unroll
      for (int mf = 0; mf < 2; ++mf)
        #pragma unroll
        for (int nf = 0; nf < 2; ++nf)
          acc[mf][nf] = __builtin_amdgcn_mfma_f32_16x16x32_bf16(
              af[mf], bfv[nf], acc[mf][nf], 0, 0, 0);
    }
    asm volatile("s_barrier" ::: "memory");
    if (c + 2 < NCH) STAGE(c + 2, c & 1);
  }
  #undef STAGE

  #pragma unroll
  for (int mf = 0; mf < 2; ++mf) {
    #pragma unroll
    for (int nf = 0; nf < 2; ++nf) {
      int col = n0 + wc * 32 + nf * 16 + fr;
      float bb;
      if (EPI == EPI_QKV)
        bb = col < 512 ? bias[col] : (col < 1024 ? bias2[col - 512] : bias3[col - 1024]);
      else
        bb = bias[col];
      #pragma unroll
      for (int j = 0; j < 4; ++j) {
        int row = m0 + wr * 32 + mf * 16 + fks * 4 + j;
        float c = acc[mf][nf][j] + bb;
        if (EPI == EPI_GELU) c = 0.5f * c * (1.0f + erff(c * 0.70710678118654752f));
        Cb[(size_t)row * N + col] = __float2bfloat16(c);
      }
    }
  }
}

// ========== gemm_ln: C = LN(A@Bt^T + bias + resid) — fused row-LN =========
// block: 512 threads (8 waves), 16 rows x 512 cols; wave w owns cols [w*64,..)
// B/A operands register-loaded directly from L2 (no LDS staging, no barriers
// in K-loop — each wave's B slice is exclusive, A rows shared but tiny).
template<int K>
__global__ __launch_bounds__(512) void gemm_ln(
    const __hip_bfloat16* __restrict__ A,    // [640][K]
    const __hip_bfloat16* __restrict__ Bt,   // [512][K]
    const float* __restrict__ bias,          // [512]
    const float* __restrict__ resid,         // [640][512] f32
    const float* __restrict__ g, const float* __restrict__ b,
    float* __restrict__ outf,                // f32 out
    __hip_bfloat16* __restrict__ outb)       // optional bf16 out
{
  constexpr int NCH = K / 64;
  const int tid = threadIdx.x, wv = tid >> 6, lane = tid & 63;
  const int fr = lane & 15, fks = lane >> 4;
  const int m0 = blockIdx.x * 16;
  const int n0 = wv * 64;

  const char* Abase = (const char*)(A + (size_t)(m0 + fr) * K);
  const char* Bb[4];
  #pragma unroll
  for (int nf = 0; nf < 4; ++nf)
    Bb[nf] = (const char*)(Bt + (size_t)(n0 + nf * 16 + fr) * K);

  bfrag8 afb[2][2];
  bfrag8 bfb[2][4][2];
  facc4 acc[4] = {};

  #define LOADC(buf, ck_) do {                                                \
    _Pragma("unroll")                                                         \
    for (int ks = 0; ks < 2; ++ks) {                                          \
      afb[buf][ks] = *(const bfrag8*)(Abase + (ck_) * 128 + ks * 64 + fks * 16); \
      _Pragma("unroll")                                                       \
      for (int nf = 0; nf < 4; ++nf)                                          \
        bfb[buf][nf][ks] = *(const bfrag8*)(Bb[nf] + (ck_) * 128 + ks * 64 + fks * 16); \
    }                                                                         \
  } while (0)

  LOADC(0, 0);
  #pragma unroll
  for (int ck = 0; ck < NCH; ++ck) {
    if (ck + 1 < NCH) LOADC((ck + 1) & 1, ck + 1);
    const int cb = ck & 1;
    #pragma unroll
    for (int ks = 0; ks < 2; ++ks)
      #pragma unroll
      for (int nf = 0; nf < 4; ++nf)
        acc[nf] = __builtin_amdgcn_mfma_f32_16x16x32_bf16(
            afb[cb][ks], bfb[cb][nf][ks], acc[nf], 0, 0, 0);
  }
  #undef LOADC

  // epilogue: bias + resid, then block-wide per-row LN over 512 cols
  float val[4][4];
  float s[4] = {0.f, 0.f, 0.f, 0.f}, q[4] = {0.f, 0.f, 0.f, 0.f};
  #pragma unroll
  for (int nf = 0; nf < 4; ++nf) {
    int col = n0 + nf * 16 + fr;
    float bc = bias[col];
    #pragma unroll
    for (int j = 0; j < 4; ++j) {
      int row = m0 + fks * 4 + j;
      float v = acc[nf][j] + bc + resid[(size_t)row * 512 + col];
      val[nf][j] = v;
      s[j] += v; q[j] += v * v;
    }
  }
  // reduce across the 16 fr-lanes (xor bits 0-3 keep fks groups intact)
  #pragma unroll
  for (int off = 1; off < 16; off <<= 1) {
    #pragma unroll
    for (int j = 0; j < 4; ++j) {
      s[j] += __shfl_xor(s[j], off);
      q[j] += __shfl_xor(q[j], off);
    }
  }
  __shared__ float sP[8][16], qP[8][16];
  __shared__ float stot[16], qtot[16];
  if (fr == 0) {
    #pragma unroll
    for (int j = 0; j < 4; ++j) {
      sP[wv][fks * 4 + j] = s[j];
      qP[wv][fks * 4 + j] = q[j];
    }
  }
  __syncthreads();
  if (tid < 16) {
    float ss = 0.f, qq = 0.f;
    #pragma unroll
    for (int w = 0; w < 8; ++w) { ss += sP[w][tid]; qq += qP[w][tid]; }
    stot[tid] = ss; qtot[tid] = qq;
  }
  __syncthreads();
  #pragma unroll
  for (int j = 0; j < 4; ++j) {
    int rloc = fks * 4 + j;
    int row = m0 + rloc;
    float u = stot[rloc] * (1.0f / 512.0f);
    float var = qtot[rloc] * (1.0f / 512.0f) - u * u;
    float rr = rsqrtf(var + 1e-12f);
    #pragma unroll
    for (int nf = 0; nf < 4; ++nf) {
      int col = n0 + nf * 16 + fr;
      float y = g[col] * ((val[nf][j] - u) * rr) + b[col];
      outf[(size_t)row * 512 + col] = y;
      if (outb) outb[(size_t)row * 512 + col] = __float2bfloat16(y);
    }
  }
}

// ========== skg: Sk = QK^T and G = Q.tiK^T (one dispatch) =================
__global__ __launch_bounds__(256) void skg_kernel(
    const __hip_bfloat16* __restrict__ qkv,
    const __hip_bfloat16* __restrict__ tikb,
    float* __restrict__ Sk, float* __restrict__ G)
{
  __shared__ u16 As[64 * 64];
  __shared__ u16 Bs[64 * 64];
  const int tid = threadIdx.x;
  const int wid = tid >> 6, lane = tid & 63;
  const int wr = wid >> 1, wc = wid & 1;
  const int fr = lane & 15, fks = lane >> 4;
  const int sr = tid >> 2, sc = (tid & 3) * 16;
  const int swz0 = sr * 128 + SWZ(sr, sc * 2);
  const int swz1 = sr * 128 + SWZ(sr, sc * 2 + 16);
  int idx = blockIdx.x;

  if (idx < 288) {
    const int z = idx / 9, rem = idx % 9;
    const int m0 = (rem / 3) * 64, n0 = (rem % 3) * 64;
    const int b = z >> 3, h = z & 7;
    const __hip_bfloat16* Aq = qkv + (size_t)b * SS * 1536 + h * 64;
    const __hip_bfloat16* Bt = qkv + (size_t)b * SS * 1536 + 512 + h * 64;
    float* C = Sk + (size_t)z * SS * SS;
    const int ar = min(m0 + sr, SS - 1), br = min(n0 + sr, SS - 1);
    uint4 av0 = *(const uint4*)(Aq + (size_t)ar * 1536 + sc);
    uint4 av1 = *(const uint4*)(Aq + (size_t)ar * 1536 + sc + 8);
    uint4 bv0 = *(const uint4*)(Bt + (size_t)br * 1536 + sc);
    uint4 bv1 = *(const uint4*)(Bt + (size_t)br * 1536 + sc + 8);
    *(uint4*)((char*)As + swz0) = av0;
    *(uint4*)((char*)As + swz1) = av1;
    *(uint4*)((char*)Bs + swz0) = bv0;
    *(uint4*)((char*)Bs + swz1) = bv1;
    __syncthreads();
    facc4 acc[2][2] = {};
    #pragma unroll
    for (int ks = 0; ks < 2; ++ks) {
      bfrag8 af[2], bfv[2];
      #pragma unroll
      for (int mf = 0; mf < 2; ++mf) {
        int rA = wr * 32 + mf * 16 + fr;
        af[mf] = *(const bfrag8*)((const char*)As + rA * 128 + SWZ(rA, 64 * ks + 16 * fks));
      }
      #pragma unroll
      for (int nf = 0; nf < 2; ++nf) {
        int rB = wc * 32 + nf * 16 + fr;
        bfv[nf] = *(const bfrag8*)((const char*)Bs + rB * 128 + SWZ(rB, 64 * ks + 16 * fks));
      }
      #pragma unroll
      for (int mf = 0; mf < 2; ++mf)
        #pragma unroll
        for (int nf = 0; nf < 2; ++nf)
          acc[mf][nf] = __builtin_amdgcn_mfma_f32_16x16x32_bf16(
              af[mf], bfv[nf], acc[mf][nf], 0, 0, 0);
    }
    #pragma unroll
    for (int mf = 0; mf < 2; ++mf)
      #pragma unroll
      for (int nf = 0; nf < 2; ++nf) {
        int col = n0 + wc * 32 + nf * 16 + fr;
        #pragma unroll
        for (int j = 0; j < 4; ++j) {
          int row = m0 + wr * 32 + mf * 16 + fks * 4 + j;
          if (row < SS && col < SS) C[row * SS + col] = acc[mf][nf][j];
        }
      }
  } else {
    int i2 = idx - 288;
    const int nb = i2 % 5, mb = (i2 / 5) % 10, h = i2 / 50;
    const int m0 = mb * 64, n0 = nb * 64;
    const __hip_bfloat16* Aq = qkv + h * 64;
    const __hip_bfloat16* Bt = tikb + h * 64;
    const int br = min(n0 + sr, NTT - 1);
    uint4 av0 = *(const uint4*)(Aq + (size_t)(m0 + sr) * 1536 + sc);
    uint4 av1 = *(const uint4*)(Aq + (size_t)(m0 + sr) * 1536 + sc + 8);
    uint4 bv0 = *(const uint4*)(Bt + (size_t)br * 512 + sc);
    uint4 bv1 = *(const uint4*)(Bt + (size_t)br * 512 + sc + 8);
    *(uint4*)((char*)As + swz0) = av0;
    *(uint4*)((char*)As + swz1) = av1;
    *(uint4*)((char*)Bs + swz0) = bv0;
    *(uint4*)((char*)Bs + swz1) = bv1;
    __syncthreads();
    facc4 acc[2][2] = {};
    #pragma unroll
    for (int ks = 0; ks < 2; ++ks) {
      bfrag8 af[2], bfv[2];
      #pragma unroll
      for (int mf = 0; mf < 2; ++mf) {
        int rA = wr * 32 + mf * 16 + fr;
        af[mf] = *(const bfrag8*)((const char*)As + rA * 128 + SWZ(rA, 64 * ks + 16 * fks));
      }
      #pragma unroll
      for (int nf = 0; nf < 2; ++nf) {
        int rB = wc * 32 + nf * 16 + fr;
        bfv[nf] = *(const bfrag8*)((const char*)Bs + rB * 128 + SWZ(rB, 64 * ks + 16 * fks));
      }
      #pragma unroll
      for (int mf = 0; mf < 2; ++mf)
        #pragma unroll
        for (int nf = 0; nf < 2; ++nf)
          acc[mf][nf] = __builtin_amdgcn_mfma_f32_16x16x32_bf16(
              af[mf], bfv[nf], acc[mf][nf], 0, 0, 0);
    }
    #pragma unroll
    for (int mf = 0; mf < 2; ++mf)
      #pragma unroll
      for (int nf = 0; nf < 2; ++nf) {
        int col = n0 + wc * 32 + nf * 16 + fr;
        #pragma unroll
        for (int j = 0; j < 4; ++j) {
          int row = m0 + wr * 32 + mf * 16 + fks * 4 + j;
          if (col < NTT)
            G[((size_t)h * MTOK + row) * NTT + col] = acc[mf][nf][j];
        }
      }
  }
}

// ---------------- attention: softmax + PV (R5 form) -----------------------
__global__ __launch_bounds__(256) void attn2(
    const __hip_bfloat16* __restrict__ qkv,
    const float* __restrict__ Sk, const float* __restrict__ G,
    const int* __restrict__ tm, const int* __restrict__ mask,
    const float* __restrict__ tiV, __hip_bfloat16* __restrict__ hh)
{
  const int h = blockIdx.y, b = blockIdx.z;
  const int ib0 = blockIdx.x * 8;
  const int tid = threadIdx.x, wv = tid >> 6, lane = tid & 63;
  __shared__ float P[8][176];
  __shared__ int tmsh[8][176];

  float rinvs[2];
  #pragma unroll
  for (int rr = 0; rr < 2; ++rr) {
    const int r = wv * 2 + rr, i = ib0 + r, m = b * SS + i;
    const float* Grow = G + ((size_t)h * MTOK + m) * NTT;
    const float* Srow = Sk + ((size_t)(b * 8 + h) * SS + i) * SS;
    const int* tmrow = tm + (size_t)m * SS;
    float sv[3];
    float mx = -1e30f;
    #pragma unroll
    for (int g = 0; g < 3; ++g) {
      int j = lane + g * 64;
      if (j < SS) {
        int t = tmrow[j];
        tmsh[r][j] = t;
        float s = (Srow[j] + Grow[t]) * 0.125f
                + 10000.0f * (1.0f - (float)mask[b * SS + j]);
        sv[g] = s; mx = fmaxf(mx, s);
      } else sv[g] = -1e30f;
    }
    #pragma unroll
    for (int off = 1; off < 64; off <<= 1) mx = fmaxf(mx, __shfl_xor(mx, off));
    float sum = 0.f;
    #pragma unroll
    for (int g = 0; g < 3; ++g) {
      int j = lane + g * 64;
      if (j < SS) { float p = expf(sv[g] - mx); P[r][j] = p; sum += p; }
    }
    #pragma unroll
    for (int off = 1; off < 64; off <<= 1) sum += __shfl_xor(sum, off);
    rinvs[rr] = 1.0f / sum;
  }

  const int r0 = wv * 2, r1 = r0 + 1;
  const int i0 = ib0 + r0, i1 = ib0 + r1;
  const __hip_bfloat16* vbase = qkv + (size_t)b * SS * 1536 + 1024 + h * 64 + lane;
  const float* tvbase = tiV + h * 64 + lane;
  float acc0 = 0.f, acc1 = 0.f;
  #pragma unroll 4
  for (int j = 0; j < SS; ++j) {
    float vv = __bfloat162float(vbase[(size_t)j * 1536]);
    float a0 = P[r0][j], a1 = P[r1][j];
    int t0 = tmsh[r0][j], t1 = tmsh[r1][j];
    acc0 += a0 * (vv + tvbase[(size_t)t0 * 512]);
    acc1 += a1 * (vv + tvbase[(size_t)t1 * 512]);
  }
  hh[((size_t)(b * SS) + i0) * DD + h * 64 + lane] = __float2bfloat16(acc0 * rinvs[0]);
  hh[((size_t)(b * SS) + i1) * DD + h * 64 + lane] = __float2bfloat16(acc1 * rinvs[1]);
}

// ---------------- launch ----------------
extern "C" void kernel_launch(void* const* d_in, const int* in_sizes, int n_in,
                              void* d_out, int out_size, void* d_ws, size_t ws_size,
                              hipStream_t stream) {
  const int*   x     = (const int*)d_in[0];
  const int*   stamp = (const int*)d_in[1];
  const int*   mask  = (const int*)d_in[2];
  const int*   tm    = (const int*)d_in[3];
  const float* tok   = (const float*)d_in[4];
  const float* month = (const float*)d_in[5];
  const float* day   = (const float*)d_in[6];
  const float* tiK   = (const float*)d_in[7];
  const float* tiV   = (const float*)d_in[8];
  const float* g0    = (const float*)d_in[9];
  const float* b0    = (const float*)d_in[10];
  const float* Wq    = (const float*)d_in[11];
  const float* bq    = (const float*)d_in[12];
  const float* Wk    = (const float*)d_in[13];
  const float* bk    = (const float*)d_in[14];
  const float* Wv    = (const float*)d_in[15];
  const float* bv    = (const float*)d_in[16];
  const float* Wo    = (const float*)d_in[17];
  const float* bo    = (const float*)d_in[18];
  const float* g1    = (const float*)d_in[19];
  const float* b1    = (const float*)d_in[20];
  const float* W1    = (const float*)d_in[21];
  const float* c1    = (const float*)d_in[22];
  const float* W2    = (const float*)d_in[23];
  const float* c2    = (const float*)d_in[24];
  const float* g2    = (const float*)d_in[25];
  const float* b2    = (const float*)d_in[26];

  float* out = (float*)d_out;
  const size_t NT = (size_t)MTOK * DD;

  char* p = (char*)d_ws;
  float* h    = (float*)p;  p += NT * 4;
  float* Skb  = (float*)p;  p += (size_t)32 * SS * SS * 4;
  float* Gb   = (float*)p;  p += (size_t)HH * MTOK * NTT * 4;
  __hip_bfloat16* h_bf   = (__hip_bfloat16*)p;  p += NT * 2;
  __hip_bfloat16* hh_bf  = (__hip_bfloat16*)p;  p += NT * 2;
  __hip_bfloat16* fb_bf  = (__hip_bfloat16*)p;  p += (size_t)MTOK * FFD * 2;
  __hip_bfloat16* qkv_bf = (__hip_bfloat16*)p;  p += (size_t)MTOK * 1536 * 2;
  __hip_bfloat16* tikb   = (__hip_bfloat16*)p;  p += (size_t)NTT * DD * 2;
  __hip_bfloat16* wqkv   = (__hip_bfloat16*)p;  p += (size_t)2 * 1536 * 512 * 2;
  __hip_bfloat16* wo_t   = (__hip_bfloat16*)p;  p += (size_t)2 * 512 * 512 * 2;
  __hip_bfloat16* w1_t   = (__hip_bfloat16*)p;  p += (size_t)2 * 2048 * 512 * 2;
  __hip_bfloat16* w2_t   = (__hip_bfloat16*)p;  p += (size_t)2 * 512 * 2048 * 2;

  prep_all<<<2305, 256, 0, stream>>>(Wq, Wk, Wv, Wo, W1, W2, tiK,
                                     wqkv, wo_t, w1_t, w2_t, tikb,
                                     x, stamp, tok, month, day, g0, b0, h, h_bf);

  for (int l = 0; l < 2; ++l) {
    gemm_ck<EPI_QKV, 512><<<dim3(24, 10), 256, 0, stream>>>(
        h_bf, wqkv + (size_t)l * 1536 * 512, bq + l*DD, bk + l*DD, bv + l*DD,
        qkv_bf, 1536);

    skg_kernel<<<688, 256, 0, stream>>>(qkv_bf, tikb, Skb, Gb);

    attn2<<<dim3(20, 8, 4), 256, 0, stream>>>(qkv_bf, Skb, Gb, tm, mask, tiV, hh_bf);

    gemm_ln<512><<<40, 512, 0, stream>>>(
        hh_bf, wo_t + (size_t)l * 512 * 512, bo + l*DD, h,
        g1 + l*DD, b1 + l*DD, h, h_bf);

    gemm_ck<EPI_GELU, 512><<<dim3(32, 10), 256, 0, stream>>>(
        h_bf, w1_t + (size_t)l * 2048 * 512, c1 + l*FFD, nullptr, nullptr,
        fb_bf, 2048);

    gemm_ln<2048><<<40, 512, 0, stream>>>(
        fb_bf, w2_t + (size_t)l * 512 * 2048, c2 + l*DD, h,
        g2 + l*DD, b2 + l*DD, (l == 1) ? out : h, (l == 1) ? nullptr : h_bf);
  }
}